// Round 1
// baseline (76.242 us; speedup 1.0000x reference)
//
#include <hip/hip_runtime.h>
#include <math.h>

#define B_  2
#define N_  2048
#define NT_ 8
#define DZ_ 16
#define H_  64
#define W_  64

#define XGRID_SIZE (B_*NT_*H_*W_*3)   // 196608 floats
#define CUT  12.0f                    // keep if dt^2+di^2 < 12 (w > 2.4e-4)
#define LCAP 384                      // per-j-tile list capacity (incl. pad)
#define LMAX (LCAP - 64)              // max real entries per list (pad = 64)

using half8   = __attribute__((ext_vector_type(8))) _Float16;
using floatx4 = __attribute__((ext_vector_type(4))) float;

#if __has_builtin(__builtin_amdgcn_exp2f)
#define EXP2(xx) __builtin_amdgcn_exp2f(xx)
#else
#define EXP2(xx) exp2f(xx)
#endif

// ---------------------------------------------------------------------------
// R12 = R11 (72.3/71.9 us) + j-locality: per-j-tile compacted lists.
//
// Key observation: with ls=0.1 the weight exp2(-(s + dj^2)) clears the
// already-applied 2.4e-4 cutoff only for |gj - x2| < ~0.44 (~28 of 64 j).
// R11 computed all 64 j for every kept entry (64*M exps/block) plus a
// cross-wave k-reduce. R12 compacts each kept entry only into the 1-3
// (avg 2.7) 16-wide j-tiles its window overlaps; wave w then owns tile w
// end-to-end: 32-entry K-steps, one MFMA/step, full sum in-wave ->
// direct store, no reduce, 3 barriers instead of 5.
// Per-thread (central block, M~267): exps 96->48, MFMA 12->6, VALU ~1/2;
// z gathers 24->48 dwords (L2-resident, 1-deep double-buffered prefetch,
// statically indexed via ks-unroll-by-2).
// Phase 1 (batched loads, validated in R11) now runs 4 ballot/scatter
// rounds per batch (one per tile), counters per tile -> less contention
// per counter.
// exp2f -> __builtin_amdgcn_exp2f: raw v_exp_f32, negate folds into the
// source modifier regardless of fast-math flags.
// Numerics: newly dropped j-terms each < 6e-5 (window cut at sqrt(14),
// wider than the s-cut at sqrt(12), +-1 j of index margin).
// ---------------------------------------------------------------------------

// one pipeline step: consume (mC,zC) for K-step KS, prefetch (mN,zN) for KS+1
#define STEP(mC, zC, mN, zN, KS)                                          \
  {                                                                       \
    const int  nxt = (KS) + 1;                                            \
    const bool pf  = (nxt < NK2);                                         \
    if (pf) {                                                             \
      const int nb = (nxt << 5) + kq;                                     \
      _Pragma("unroll")                                                   \
      for (int jj = 0; jj < 8; ++jj) mN[jj] = mw[nb + jj];                \
    }                                                                     \
    half8 bf, af;                                                         \
    _Pragma("unroll")                                                     \
    for (int jj = 0; jj < 8; ++jj) bf[jj] = (_Float16)zC[jj];             \
    _Pragma("unroll")                                                     \
    for (int jj = 0; jj < 8; ++jj) {                                      \
      float d = ajv - mC[jj].y;                                           \
      af[jj] = (_Float16)EXP2(-fmaf(d, d, mC[jj].x));                     \
    }                                                                     \
    if (pf) {                                                             \
      _Pragma("unroll")                                                   \
      for (int jj = 0; jj < 8; ++jj)                                      \
        zN[jj] = zb[(size_t)__float_as_int(mN[jj].z) * DZ_ + col];        \
    }                                                                     \
    acc = __builtin_amdgcn_mfma_f32_16x16x32_f16(af, bf, acc, 0, 0, 0);   \
  }

__global__ __launch_bounds__(256, 4) void fused_kernel(
    const float* __restrict__ x,      // [B][N][3]
    const float* __restrict__ z,      // [B][N][16]
    const float* __restrict__ tg,     // [B][NT]
    const float* __restrict__ lsp,    // [3]
    float* __restrict__ out)          // x_grid (196608) ++ z_grid (1048576)
{
    const int i    = blockIdx.x & 63;
    const int t    = (blockIdx.x >> 6) & 7;
    const int b    = blockIdx.x >> 9;
    const int tid  = threadIdx.x;
    const int w    = tid >> 6;        // wave id = j-tile id
    const int lane = tid & 63;
    const int quad = lane >> 4;       // 0..3
    const int col  = lane & 15;       // A m-index (j in tile) / B n-index (e)

    const float step    = 2.0f / 63.0f;
    const float invstep = 31.5f;      // 63/2
    const float C       = 0.84932180f; // sqrt(0.5 * log2(e))

    const float r0 = C / (1e-5f + log1pf(expf(lsp[0])));
    const float r1 = C / (1e-5f + log1pf(expf(lsp[1])));
    const float r2 = C / (1e-5f + log1pf(expf(lsp[2])));
    const float RADJ = 3.74165739f / r2;   // sqrt(14) in raw gj units

    const float tval = tg[b*NT_ + t];
    const float gi   = -1.0f + step * (float)i;

    // per-j-tile lists: {s, cx, idx_bits, unused} per entry
    __shared__ float4 meta[4][LCAP];   // 24576 B
    __shared__ int    cnt[4];

    if (tid < 4) cnt[tid] = 0;
    __syncthreads();

    // ---- phase 1: cull + j-windowed compact into 4 tile lists ----
    const float* __restrict__ xb = x + b*N_*3;
    {
        float px0[8], px1[8], px2[8];
        #pragma unroll
        for (int r = 0; r < 8; ++r) {
            int k = r*256 + tid;
            px0[r] = xb[k*3 + 0];
            px1[r] = xb[k*3 + 1];
            px2[r] = xb[k*3 + 2];
        }
        #pragma unroll
        for (int r = 0; r < 8; ++r) {
            int k = r*256 + tid;
            float dt = (tval - px0[r]) * r0;
            float di = (gi   - px1[r]) * r1;
            float sq = fmaf(dt, dt, di*di);
            bool keep = (sq < CUT);
            float xr = px2[r];
            // j-window [jlo,jhi] where dj^2 < 14, +-1 index margin
            int jlo = (int)ceilf ((xr - RADJ + 1.0f) * invstep) - 1;
            int jhi = (int)floorf((xr + RADJ + 1.0f) * invstep) + 1;
            jlo = jlo < 0  ? 0  : jlo;
            jhi = jhi > 63 ? 63 : jhi;
            const int tlo = jlo >> 4, thi = jhi >> 4;
            const float4 val = make_float4(sq, xr * r2, __int_as_float(k), 0.f);
            #pragma unroll
            for (int tt = 0; tt < 4; ++tt) {
                bool kt = keep && (tt >= tlo) && (tt <= thi);
                unsigned long long mb = __ballot(kt);
                int cb = __popcll(mb);
                int base = 0;
                if (lane == 0 && cb) base = atomicAdd(&cnt[tt], cb);
                base = __shfl(base, 0, 64);
                if (kt) {
                    int pos = base + __popcll(mb & ((1ull << lane) - 1ull));
                    if (pos < LMAX) meta[tt][pos] = val;
                }
            }
        }
    }

    // x_grid row for this (b,t,i): 192 floats, coalesced
    if (tid < 192) {
        int jj = tid / 3;
        int c  = tid - jj*3;
        float gj = -1.0f + step * (float)jj;
        float v  = (c == 0) ? tval : ((c == 1) ? gi : gj);
        out[(size_t)blockIdx.x * 192 + tid] = v;
    }

    __syncthreads();
    // pad each list by 64 entries (s huge -> exp2 -> 0); 256 threads = 4x64
    {
        int tt = tid >> 6, o = tid & 63;
        int Lt = min(cnt[tt], LMAX);
        meta[tt][Lt + o] = make_float4(1e9f, 0.f, __int_as_float(0), 0.f);
    }
    __syncthreads();

    // ---- phase 2: wave w owns j-tile w; 32-entry K-steps, no barriers ----
    const float* __restrict__ zb = z + b*N_*DZ_;
    const float4* mw = &meta[w][0];
    const int kq  = quad << 3;                 // lane's k-base within a step
    const int Lw  = min(cnt[w], LMAX);
    const int NK2 = (((Lw + 31) >> 5) + 1) & ~1;   // steps, rounded to even

    // A m-index = col -> this lane's single j coordinate (scaled)
    const float ajv = (-1.0f + step * (float)((w << 4) + col)) * r2;

    floatx4 acc = {0.f, 0.f, 0.f, 0.f};
    float4 mA[8], mB[8];
    float  zA[8], zB[8];

    // prologue: step 0 meta + z (pads make all indices valid even if Lw==0)
    #pragma unroll
    for (int jj = 0; jj < 8; ++jj) mA[jj] = mw[kq + jj];
    #pragma unroll
    for (int jj = 0; jj < 8; ++jj)
        zA[jj] = zb[(size_t)__float_as_int(mA[jj].z) * DZ_ + col];

    for (int ks = 0; ks < NK2; ks += 2) {
        STEP(mA, zA, mB, zB, ks);
        STEP(mB, zB, mA, zA, ks + 1);
    }

    // ---- epilogue: direct store (wave owns its 16 j rows completely) ----
    // D layout: row = quad*4 + r (j in tile), col = lane&15 (e)
    float* og = out + XGRID_SIZE + (size_t)blockIdx.x * (W_ * DZ_);
    #pragma unroll
    for (int r = 0; r < 4; ++r)
        og[((w << 4) + (quad << 2) + r) * DZ_ + col] = acc[r];
}

extern "C" void kernel_launch(void* const* d_in, const int* in_sizes, int n_in,
                              void* d_out, int out_size, void* d_ws, size_t ws_size,
                              hipStream_t stream) {
    const float* x   = (const float*)d_in[0];   // [B][N][3]
    const float* z   = (const float*)d_in[1];   // [B][N][16]
    const float* tg  = (const float*)d_in[2];   // [B][NT]
    const float* lsp = (const float*)d_in[3];   // [3]

    float* out = (float*)d_out;

    // 1024 blocks, one per (b,t,i) row; no workspace, no memset, no atomics.
    fused_kernel<<<1024, 256, 0, stream>>>(x, z, tg, lsp, out);
}

// Round 2
// 69.555 us; speedup vs baseline: 1.0961x; 1.0961x over previous
//
#include <hip/hip_runtime.h>
#include <math.h>

#define B_  2
#define N_  2048
#define NT_ 8
#define DZ_ 16
#define H_  64
#define W_  64

#define XGRID_SIZE (B_*NT_*H_*W_*3)   // 196608 floats
#define CUT 12.0f                     // keep if dt^2+di^2 < 12 (w > 2.4e-4)
#define CH  128                       // K-chunk: 4 waves x K=32

using half8   = __attribute__((ext_vector_type(8))) _Float16;
using floatx4 = __attribute__((ext_vector_type(4))) float;

#if __has_builtin(__builtin_amdgcn_exp2f)
#define EXP2(xx) __builtin_amdgcn_exp2f(xx)
#else
#define EXP2(xx) exp2f(xx)
#endif

// ---------------------------------------------------------------------------
// R13 = R11's phase 2 (validated, best 71.9) + restructured phase 1.
//
// R12 post-mortem (j-tiled lists, 76.2): max-wave exp reduction was only
// ~30% (entry window 0.88 vs tile width 0.51 -> 2.7x list duplication),
// while z-gathers rose 2.7x and ballot/atomic rounds rose 4x. Net +3.4 us.
// Reverted. Its one usable measurement: each ballot->atomic->shfl
// compaction round costs ~150 ns of serial chain.
//
// Phase-1 changes vs R11:
//  * per-thread contiguous entries (k = tid*8+r): the 24 stride-12B scalar
//    x-loads become 6 dwordx4 loads (4x fewer VMEM issues, L2-resident).
//  * compaction via 4-ballot bit-decomposed prefix sum (cnt in [0,8]):
//    pre = sum_bit popcll(ballot(cnt>>bit&1) & below)<<bit. No atomics,
//    no shfl broadcast chains, no s_cnt init barrier. Cross-wave offset
//    through a 4-int LDS combine under the barrier we already pay.
//  * pad runs concurrently with scatter (M known from wsum right after
//    the first barrier; pad slots [M, M+CH) are disjoint from scatter).
//
// Phase 2 (unchanged from R11): wave w owns k-subrange [w*32,w*32+32) of
// each 128-entry chunk, 4 j-tiles from one B-frag gathered from global z
// (64 B coalesced per quad, L2-resident), 1-chunk-deep prefetch, NO
// barriers in the K-loop. MFMA f16 16x16x32. Epilogue: stride-17 LDS
// reduce of 4 k-partials, coalesced float4 stores. No atomics anywhere.
// ---------------------------------------------------------------------------
__global__ __launch_bounds__(256, 4) void fused_kernel(
    const float* __restrict__ x,      // [B][N][3]
    const float* __restrict__ z,      // [B][N][16]
    const float* __restrict__ tg,     // [B][NT]
    const float* __restrict__ lsp,    // [3]
    float* __restrict__ out)          // x_grid (196608) ++ z_grid (1048576)
{
    const int i    = blockIdx.x & 63;
    const int t    = (blockIdx.x >> 6) & 7;
    const int b    = blockIdx.x >> 9;
    const int tid  = threadIdx.x;
    const int w    = tid >> 6;        // wave id = k-subrange
    const int lane = tid & 63;
    const int quad = lane >> 4;       // 0..3
    const int col  = lane & 15;       // A row (j in tile) / B col (e)

    const float step = 2.0f / 63.0f;
    const float C    = 0.84932180f;   // sqrt(0.5 * log2(e))

    const float r0 = C / (1e-5f + log1pf(expf(lsp[0])));
    const float r1 = C / (1e-5f + log1pf(expf(lsp[1])));
    const float r2 = C / (1e-5f + log1pf(expf(lsp[2])));

    const float tval = tg[b*NT_ + t];
    const float gi   = -1.0f + step * (float)i;

    union REDU {
        float2 cuc[N_ + CH];           // {s, cx}: 17408 B (phases 1-2)
        float  red[4][64][DZ_ + 1];    // 17408 B (epilogue reduce)
    };
    __shared__ REDU sm;
    __shared__ int  cidx[N_ + CH];     // 8704 B
    __shared__ int  wsum[4];

    // ---- phase 1: cull + prefix-sum compaction (no atomics) ----
    // Thread owns 8 consecutive entries k = tid*8 + r -> x rows load as
    // 6 float4s (96 B/thread, one vmcnt window).
    const float* __restrict__ xb = x + b*N_*3;
    float sq[8], cx[8];
    int keepm = 0;
    {
        const float4* __restrict__ xb4 = (const float4*)xb;
        float f[24];
        #pragma unroll
        for (int q = 0; q < 6; ++q) {
            float4 v = xb4[tid*6 + q];
            f[q*4+0] = v.x; f[q*4+1] = v.y; f[q*4+2] = v.z; f[q*4+3] = v.w;
        }
        #pragma unroll
        for (int r = 0; r < 8; ++r) {
            float dt = (tval - f[3*r+0]) * r0;
            float di = (gi   - f[3*r+1]) * r1;
            sq[r] = fmaf(dt, dt, di*di);
            cx[r] = f[3*r+2] * r2;
            if (sq[r] < CUT) keepm |= (1 << r);
        }
    }
    const int cnt = __popc(keepm);
    // ballot-decomposed exclusive prefix over the wave (cnt in [0,8])
    const unsigned long long below = (1ull << lane) - 1ull;
    int pre = 0, wtot = 0;
    #pragma unroll
    for (int bit = 0; bit < 4; ++bit) {
        unsigned long long bb = __ballot((cnt >> bit) & 1);
        pre  += __popcll(bb & below) << bit;
        wtot += __popcll(bb) << bit;
    }
    if (lane == 0) wsum[w] = wtot;
    __syncthreads();

    int woff = 0, M = 0;
    #pragma unroll
    for (int ww = 0; ww < 4; ++ww) {
        int s = wsum[ww];
        woff += (ww < w) ? s : 0;
        M    += s;
    }
    {
        int pos = woff + pre;
        #pragma unroll
        for (int r = 0; r < 8; ++r) {
            if ((keepm >> r) & 1) {
                sm.cuc[pos] = make_float2(sq[r], cx[r]);
                cidx[pos]   = tid*8 + r;
                ++pos;
            }
        }
    }
    // pad: disjoint from scatter ([M, M+CH)); s huge -> exp2 -> 0
    if (tid < CH) {
        sm.cuc[M + tid] = make_float2(1e9f, 0.f);
        cidx[M + tid]   = 0;
    }

    // x_grid row for this (b,t,i): 192 floats, coalesced
    if (tid < 192) {
        int jj = tid / 3;
        int c  = tid - jj*3;
        float gj = -1.0f + step * (float)jj;
        float v  = (c == 0) ? tval : ((c == 1) ? gi : gj);
        out[(size_t)blockIdx.x * 192 + tid] = v;
    }
    __syncthreads();

    const int NC = (M + CH - 1) / CH;  // 128-entry chunks

    // ---- phase 2: barrier-free MFMA K-loop (unchanged from R11) ----
    const float* __restrict__ zb = z + b*N_*DZ_;
    const int koff = w*32 + (quad << 3);   // this lane's k-base within a chunk

    const float aj0 = (-1.0f + step * (float)( 0 + col)) * r2;
    const float aj1 = (-1.0f + step * (float)(16 + col)) * r2;
    const float aj2 = (-1.0f + step * (float)(32 + col)) * r2;
    const float aj3 = (-1.0f + step * (float)(48 + col)) * r2;

    floatx4 acc0 = {0.f,0.f,0.f,0.f};
    floatx4 acc1 = {0.f,0.f,0.f,0.f};
    floatx4 acc2 = {0.f,0.f,0.f,0.f};
    floatx4 acc3 = {0.f,0.f,0.f,0.f};

    // prologue: B dwords for chunk 0 (pads make indices always valid)
    float zreg[8];
    {
        int idx[8];
        #pragma unroll
        for (int jj = 0; jj < 8; ++jj) idx[jj] = cidx[koff + jj];
        #pragma unroll
        for (int jj = 0; jj < 8; ++jj)
            zreg[jj] = zb[(size_t)idx[jj] * DZ_ + col];
    }

    for (int c = 0; c < NC; ++c) {
        // pack current B fragment
        half8 bf;
        #pragma unroll
        for (int jj = 0; jj < 8; ++jj) bf[jj] = (_Float16)zreg[jj];

        // meta for current chunk (quad-uniform broadcast, 8 entries/lane)
        const int base = c*CH + koff;
        float2 mm[8];
        #pragma unroll
        for (int jj = 0; jj < 8; ++jj) mm[jj] = sm.cuc[base + jj];

        // prefetch next chunk's B dwords (land during exp/MFMA below)
        if (c + 1 < NC) {
            const int base2 = (c + 1)*CH + koff;
            int idx[8];
            #pragma unroll
            for (int jj = 0; jj < 8; ++jj) idx[jj] = cidx[base2 + jj];
            #pragma unroll
            for (int jj = 0; jj < 8; ++jj)
                zreg[jj] = zb[(size_t)idx[jj] * DZ_ + col];
        }

        // A fragments for the 4 j-tiles
        half8 a0, a1, a2, a3;
        #pragma unroll
        for (int jj = 0; jj < 8; ++jj) {
            float s  = mm[jj].x;
            float cxv = mm[jj].y;
            float d0 = aj0 - cxv;
            float d1 = aj1 - cxv;
            float d2 = aj2 - cxv;
            float d3 = aj3 - cxv;
            a0[jj] = (_Float16)EXP2(-fmaf(d0, d0, s));
            a1[jj] = (_Float16)EXP2(-fmaf(d1, d1, s));
            a2[jj] = (_Float16)EXP2(-fmaf(d2, d2, s));
            a3[jj] = (_Float16)EXP2(-fmaf(d3, d3, s));
        }

        acc0 = __builtin_amdgcn_mfma_f32_16x16x32_f16(a0, bf, acc0, 0, 0, 0);
        acc1 = __builtin_amdgcn_mfma_f32_16x16x32_f16(a1, bf, acc1, 0, 0, 0);
        acc2 = __builtin_amdgcn_mfma_f32_16x16x32_f16(a2, bf, acc2, 0, 0, 0);
        acc3 = __builtin_amdgcn_mfma_f32_16x16x32_f16(a3, bf, acc3, 0, 0, 0);
    }

    __syncthreads();   // all cuc reads done before red overlays it

    // ---- epilogue: reduce 4 k-partials across waves, store z_grid ----
    // D layout: row = quad*4 + reg, col = lane&15.
    #pragma unroll
    for (int r = 0; r < 4; ++r) sm.red[w][ 0 + quad*4 + r][col] = acc0[r];
    #pragma unroll
    for (int r = 0; r < 4; ++r) sm.red[w][16 + quad*4 + r][col] = acc1[r];
    #pragma unroll
    for (int r = 0; r < 4; ++r) sm.red[w][32 + quad*4 + r][col] = acc2[r];
    #pragma unroll
    for (int r = 0; r < 4; ++r) sm.red[w][48 + quad*4 + r][col] = acc3[r];
    __syncthreads();

    const int jj = tid >> 2;               // 0..63
    const int eg = (tid & 3) * 4;          // 0,4,8,12
    float4 s4 = make_float4(0.f, 0.f, 0.f, 0.f);
    #pragma unroll
    for (int ww = 0; ww < 4; ++ww) {
        s4.x += sm.red[ww][jj][eg + 0];
        s4.y += sm.red[ww][jj][eg + 1];
        s4.z += sm.red[ww][jj][eg + 2];
        s4.w += sm.red[ww][jj][eg + 3];
    }
    float* og = out + XGRID_SIZE + (size_t)blockIdx.x * (W_ * DZ_);
    *(float4*)(og + jj*DZ_ + eg) = s4;
}

extern "C" void kernel_launch(void* const* d_in, const int* in_sizes, int n_in,
                              void* d_out, int out_size, void* d_ws, size_t ws_size,
                              hipStream_t stream) {
    const float* x   = (const float*)d_in[0];   // [B][N][3]
    const float* z   = (const float*)d_in[1];   // [B][N][16]
    const float* tg  = (const float*)d_in[2];   // [B][NT]
    const float* lsp = (const float*)d_in[3];   // [3]

    float* out = (float*)d_out;

    // 1024 blocks, one per (b,t,i) row; no workspace, no memset, no atomics.
    fused_kernel<<<1024, 256, 0, stream>>>(x, z, tg, lsp, out);
}